// Round 2
// baseline (208.463 us; speedup 1.0000x reference)
//
#include <hip/hip_runtime.h>
#include <hip/hip_bf16.h>

typedef __attribute__((ext_vector_type(8))) short shortx8;
typedef __attribute__((ext_vector_type(4))) float floatx4;
typedef __attribute__((ext_vector_type(4))) unsigned uintx4;
typedef __attribute__((ext_vector_type(2))) unsigned uintx2;

#define B_ 2
#define T_ 2048
#define D_ 1024
#define H_ 16
#define HD_ 64
#define SCALE 0.125f
// log2(e)-folded constants: Q is pre-scaled by SCALE*log2e, softmax uses exp2.
#define QSCALE 0.18033688011112042f   /* 0.125 * log2(e) */
#define SMAX2 23.083120654223414f     /* 16 * log2(e) */
#define FULLH ((size_t)B_ * H_ * T_ * HD_)

// async global->LDS, 16B per lane; LDS dest = wave-uniform base + lane*16
#define GLDS16(g, l) __builtin_amdgcn_global_load_lds( \
    (__attribute__((address_space(1))) void*)(g), \
    (__attribute__((address_space(3))) void*)(l), 16, 0, 0)

__device__ __forceinline__ short f2bf(float f) {
    union { float f; unsigned u; } v; v.f = f;
    unsigned r = v.u + 0x7FFFu + ((v.u >> 16) & 1u);
    return (short)(r >> 16);
}

__device__ __forceinline__ unsigned pk2(float x, float y) {
    union { __hip_bfloat162 h; unsigned u; } t;
    t.h = __float22bfloat162_rn(make_float2(x, y));
    return t.u;
}

__device__ __forceinline__ shortx8 cvt8(floatx4 a, floatx4 b) {
    uintx4 r = { pk2(a[0], a[1]), pk2(a[2], a[3]), pk2(b[0], b[1]), pk2(b[2], b[3]) };
    return __builtin_bit_cast(shortx8, r);
}

__device__ __forceinline__ float ex2(float x) {
#if __has_builtin(__builtin_amdgcn_exp2f)
    return __builtin_amdgcn_exp2f(x);
#else
    return exp2f(x);
#endif
}

// ---------------- fp32 -> bf16 bulk convert (x + w_qkv merged, one launch) ----
// grid 3584: blocks [0,2048) -> x (524288 groups), [2048,3584) -> wqkv (393216).
__global__ __launch_bounds__(256) void cvt_xw(const float* __restrict__ x,
                                              const float* __restrict__ wqkv,
                                              short* __restrict__ xbf,
                                              short* __restrict__ wbf) {
    int i = blockIdx.x * 256 + threadIdx.x;
    const float* src; short* dst; int o;
    if (i < 524288) { src = x; dst = xbf; o = i; }
    else            { src = wqkv; dst = wbf; o = i - 524288; }
    const floatx4* p = reinterpret_cast<const floatx4*>(src) + (size_t)o * 2;
    *(reinterpret_cast<shortx8*>(dst) + o) = cvt8(p[0], p[1]);
}

// ================= FAST PATH (bf16 inputs, m97-style) =================
// 128x128 tile, BK=64, global_load_lds staging with XOR chunk swizzle.
// LDS layout: slot(row, sc) holds logical chunk sc ^ (row&7); rows stride 64.

// Q/K/V projection. grid (24,32): n0g = bx*128 (sel = n0g>>10), m-tile by.
__global__ __launch_bounds__(256) void qkv_fast(const short* __restrict__ xbf,
                                                const short* __restrict__ wbf,
                                                short* __restrict__ qout,
                                                short* __restrict__ kv) {
    __shared__ __align__(16) short As[128 * 64];
    __shared__ __align__(16) short Bs[128 * 64];

    const int tid = threadIdx.x;
    const int wv = tid >> 6;
    const int l  = tid & 63;
    const int ln = l & 15;
    const int quad = l >> 4;
    const int rowb = quad << 2;
    const int wm = wv >> 1, wn = wv & 1;
    const int m0 = blockIdx.y * 128;
    const int n0g = blockIdx.x * 128;

    const int lr = l >> 3, lc = l & 7;
    const int gcol = (lc ^ lr) << 3;                 // swizzled source chunk
    const short* agp = xbf + (size_t)(m0 + wv * 32 + lr) * D_ + gcol;
    const short* bgp = wbf + (size_t)(n0g + wv * 32 + lr) * D_ + gcol;
    short* aldsb = As + wv * 32 * 64;
    short* bldsb = Bs + wv * 32 * 64;

    floatx4 acc[4][4] = {};

    for (int k0 = 0; k0 < D_; k0 += 64) {
        __syncthreads();
#pragma unroll
        for (int c = 0; c < 4; ++c) {
            GLDS16(agp + (size_t)(c * 8) * D_ + k0, aldsb + c * 512);
            GLDS16(bgp + (size_t)(c * 8) * D_ + k0, bldsb + c * 512);
        }
        __syncthreads();

#pragma unroll
        for (int kk = 0; kk < 2; ++kk) {
            const int csw = (kk << 2) + quad;
            const int sw = (csw ^ (ln & 7)) << 3;
            shortx8 af[4], bf[4];
#pragma unroll
            for (int i = 0; i < 4; ++i)
                af[i] = *reinterpret_cast<const shortx8*>(&As[((wm * 64 + i * 16 + ln) << 6) + sw]);
#pragma unroll
            for (int j = 0; j < 4; ++j)
                bf[j] = *reinterpret_cast<const shortx8*>(&Bs[((wn * 64 + j * 16 + ln) << 6) + sw]);
#pragma unroll
            for (int i = 0; i < 4; ++i)
#pragma unroll
                for (int j = 0; j < 4; ++j)
                    acc[i][j] = __builtin_amdgcn_mfma_f32_16x16x32_bf16(af[i], bf[j], acc[i][j], 0, 0, 0);
        }
    }

    const int sel = n0g >> 10;
    const int bb = m0 >> 11;
    const int t0w = (m0 + wm * 64) & (T_ - 1);
    const int h = ((n0g + wn * 64) >> 6) & 15;

    if (sel < 2) {
        short* dst = (sel == 0) ? qout : kv;
        const float sc = (sel == 0) ? QSCALE : 1.0f;   // Q carries log2e
        const size_t hb = (size_t)(bb * H_ + h) * T_;
#pragma unroll
        for (int i = 0; i < 4; ++i)
#pragma unroll
            for (int r = 0; r < 4; ++r) {
                int t = t0w + i * 16 + rowb + r;
#pragma unroll
                for (int j = 0; j < 4; ++j)
                    dst[(hb + t) * HD_ + j * 16 + ln] = f2bf(acc[i][j][r] * sc);
            }
    } else {
        // V -> dim-major [b][h][d][t], 2-pass per-wave LDS transpose (As/Bs dead)
        __syncthreads();
        short* tb = (wv < 2) ? (As + wv * 4096) : (Bs + (wv - 2) * 4096);  // 32x72 region
        short* vhead = kv + FULLH + (size_t)(bb * H_ + h) * HD_ * T_;
        const int dl = l & 31, th = (l >> 5) << 5;
#pragma unroll
        for (int p = 0; p < 2; ++p) {
#pragma unroll
            for (int i = 0; i < 4; ++i)
#pragma unroll
                for (int jj = 0; jj < 2; ++jj) {
                    int j = 2 * p + jj;
#pragma unroll
                    for (int r = 0; r < 4; ++r)
                        tb[(jj * 16 + ln) * 72 + i * 16 + rowb + r] = f2bf(acc[i][j][r]);
                }
            short* vd = vhead + (size_t)(p * 32 + dl) * T_ + t0w + th;
#pragma unroll
            for (int seg = 0; seg < 4; ++seg)
                *reinterpret_cast<shortx8*>(vd + seg * 8) =
                    *reinterpret_cast<const shortx8*>(&tb[dl * 72 + th + seg * 8]);
        }
    }
}

// Final projection. grid (8,32). A = attn out, bf16 head-major. W bf16 row-major.
__global__ __launch_bounds__(256) void out_fast(const short* __restrict__ Abf,
                                                const short* __restrict__ wbf,
                                                float* __restrict__ out) {
    __shared__ __align__(16) short As[128 * 64];
    __shared__ __align__(16) short Bs[128 * 64];

    const int tid = threadIdx.x;
    const int wv = tid >> 6;
    const int l  = tid & 63;
    const int ln = l & 15;
    const int quad = l >> 4;
    const int rowb = quad << 2;
    const int wm = wv >> 1, wn = wv & 1;
    const int m0 = blockIdx.y * 128;
    const int n0g = blockIdx.x * 128;

    const int lr = l >> 3, lc = l & 7;
    const int gcol = (lc ^ lr) << 3;
    const short* bgp = wbf + (size_t)(n0g + wv * 32 + lr) * D_ + gcol;
    short* aldsb = As + wv * 32 * 64;
    short* bldsb = Bs + wv * 32 * 64;

    size_t abase[4];
#pragma unroll
    for (int c = 0; c < 4; ++c) {
        int m = m0 + wv * 32 + c * 8 + lr;
        int bb2 = m >> 11, t = m & (T_ - 1);
        abase[c] = ((size_t)(bb2 * H_) * T_ + t) * HD_ + gcol;
    }

    floatx4 acc[4][4] = {};

    for (int k0 = 0; k0 < D_; k0 += 64) {
        const size_t hoff = (size_t)(k0 >> 6) * T_ * HD_;
        __syncthreads();
#pragma unroll
        for (int c = 0; c < 4; ++c) {
            GLDS16(Abf + abase[c] + hoff, aldsb + c * 512);
            GLDS16(bgp + (size_t)(c * 8) * D_ + k0, bldsb + c * 512);
        }
        __syncthreads();

#pragma unroll
        for (int kk = 0; kk < 2; ++kk) {
            const int csw = (kk << 2) + quad;
            const int sw = (csw ^ (ln & 7)) << 3;
            shortx8 af[4], bf[4];
#pragma unroll
            for (int i = 0; i < 4; ++i)
                af[i] = *reinterpret_cast<const shortx8*>(&As[((wm * 64 + i * 16 + ln) << 6) + sw]);
#pragma unroll
            for (int j = 0; j < 4; ++j)
                bf[j] = *reinterpret_cast<const shortx8*>(&Bs[((wn * 64 + j * 16 + ln) << 6) + sw]);
#pragma unroll
            for (int i = 0; i < 4; ++i)
#pragma unroll
                for (int j = 0; j < 4; ++j)
                    acc[i][j] = __builtin_amdgcn_mfma_f32_16x16x32_bf16(af[i], bf[j], acc[i][j], 0, 0, 0);
        }
    }

#pragma unroll
    for (int i = 0; i < 4; ++i)
#pragma unroll
        for (int r = 0; r < 4; ++r) {
            int m = m0 + wm * 64 + i * 16 + rowb + r;
#pragma unroll
            for (int j = 0; j < 4; ++j)
                out[(size_t)m * D_ + n0g + wn * 64 + j * 16 + ln] = acc[i][j][r];
        }
}

// ---------------- flash attention (shared by both paths) ----------------
// Complementary q-tile pairing: block p handles q-tiles (31-p, p) JOINTLY in
// one kb loop -> uniform work (33 tile-computes/block), 512 blocks ALL
// co-resident (2/CU), K/V staging + barriers + Ks/Vt reads shared between
// the two tiles. XCD-swizzled: 4 heads per XCD for KV L2 locality.
// Blocks >= 512 (fast path only) convert w_out fp32->bf16 alongside.
__global__ __launch_bounds__(256, 4) void attn(const short* __restrict__ qws,
                                               const short* __restrict__ kv,
                                               short* ao,
                                               const float* __restrict__ wout,
                                               short* __restrict__ wobf) {
    if (blockIdx.x >= 512) {
        int i = (blockIdx.x - 512) * 256 + threadIdx.x;   // 512 blocks -> 131072 groups
        const floatx4* p = reinterpret_cast<const floatx4*>(wout) + (size_t)i * 2;
        *(reinterpret_cast<shortx8*>(wobf) + i) = cvt8(p[0], p[1]);
        return;
    }

    __shared__ __align__(16) short Ks[64][72];
    __shared__ __align__(16) short Vt[64][72];
    // stride 20 shorts (40B): transpose reads are 2-way (free, m136); 8B
    // uintx2 writes stay aligned (row*40 + quad*8).
    __shared__ __align__(16) short PtH[4][64][20];
    __shared__ __align__(16) short PtL[4][64][20];

    const int tid = threadIdx.x;
    const int wv   = tid >> 6;
    const int l    = tid & 63;
    const int ln   = l & 15;
    const int quad = l >> 4;
    const int qd   = quad << 3;
    const int rowb = quad << 2;

    const int xcd  = blockIdx.x & 7;
    const int slot = blockIdx.x >> 3;        // 0..63
    const int bh   = xcd * 4 + (slot & 3);   // 4 heads per XCD
    const int pr   = slot >> 2;              // 0..15
    const int qbH  = 31 - pr;                // heavy tile
    const int qbL  = pr;                     // complementary light tile
    const int h    = bh & 15;
    const int b    = bh >> 4;

    // slope in log2 domain (Q already carries SCALE*log2e)
    const float slope2 = 1.4426950408889634f * exp2f(-(float)(h + 1) * 0.0625f);
    const size_t koff = (size_t)(b * H_ + h) * T_ * HD_;
    const int q0H = qbH * 64 + wv * 16;
    const int q0L = qbL * 64 + wv * 16;

    shortx8 qfH[2], qfL[2];
#pragma unroll
    for (int kk = 0; kk < 2; ++kk) {
        qfH[kk] = *reinterpret_cast<const shortx8*>(&qws[koff + (size_t)(q0H + ln) * HD_ + kk * 32 + qd]);
        qfL[kk] = *reinterpret_cast<const shortx8*>(&qws[koff + (size_t)(q0L + ln) * HD_ + kk * 32 + qd]);
    }

    const int r0 = tid >> 3, c0 = (tid & 7) << 3, r1 = r0 + 32;
    const short* kbase = kv + koff;
    const short* vbase = kv + FULLH + koff;
    shortx8 kA, kB, vA, vB;
    auto FETCH = [&](int kb) {
        const short* kp = kbase + ((size_t)(kb * 64) << 6);
        kA = *reinterpret_cast<const shortx8*>(kp + ((size_t)r0 << 6) + c0);
        kB = *reinterpret_cast<const shortx8*>(kp + ((size_t)r1 << 6) + c0);
        const short* vp = vbase + kb * 64;
        vA = *reinterpret_cast<const shortx8*>(vp + ((size_t)r0 << 11) + c0);
        vB = *reinterpret_cast<const shortx8*>(vp + ((size_t)r1 << 11) + c0);
    };

    floatx4 oaccH[4] = {}, oaccL[4] = {};
    floatx4 lsumH = {}, lsumL = {};
    const shortx8 ones = {16256, 16256, 16256, 16256, 16256, 16256, 16256, 16256};
    const float base0H = -SMAX2 - slope2 * (float)(q0H + rowb);
    const float base0L = -SMAX2 - slope2 * (float)(q0L + rowb);
    float snc16[4];
#pragma unroll
    for (int nc = 0; nc < 4; ++nc) snc16[nc] = slope2 * (float)(nc * 16);

    FETCH(0);
    for (int kb = 0; kb <= qbH; ++kb) {
        __syncthreads();
        *reinterpret_cast<shortx8*>(&Ks[r0][c0]) = kA;
        *reinterpret_cast<shortx8*>(&Ks[r1][c0]) = kB;
        *reinterpret_cast<shortx8*>(&Vt[r0][c0]) = vA;
        *reinterpret_cast<shortx8*>(&Vt[r1][c0]) = vB;
        __syncthreads();
        if (kb < qbH) FETCH(kb + 1);

        const bool diagH = (kb == qbH);
        const bool liveL = (kb <= qbL);
        const bool diagL = (kb == qbL);
        const int kln = kb * 64 + ln;
        const float bb0H = slope2 * (float)kln + base0H;
        const float bb0L = slope2 * (float)kln + base0L;
        float bbrH[4], bbrL[4];
#pragma unroll
        for (int r = 0; r < 4; ++r) {
            bbrH[r] = bb0H - slope2 * (float)r;
            bbrL[r] = bb0L - slope2 * (float)r;
        }

#pragma unroll
        for (int nc = 0; nc < 4; ++nc) {
            floatx4 sH = {}, sL = {};
            const bool doH = !diagH || (nc <= wv);
            const bool doL = liveL && (!diagL || (nc <= wv));
#pragma unroll
            for (int kk = 0; kk < 2; ++kk) {
                shortx8 bfr = *reinterpret_cast<const shortx8*>(&Ks[nc * 16 + ln][kk * 32 + qd]);
                if (doH) sH = __builtin_amdgcn_mfma_f32_16x16x32_bf16(qfH[kk], bfr, sH, 0, 0, 0);
                if (doL) sL = __builtin_amdgcn_mfma_f32_16x16x32_bf16(qfL[kk], bfr, sL, 0, 0, 0);
            }
            // heavy pack + store
            if (!diagH) {
                uintx2 pkd = { pk2(ex2(sH[0] + bbrH[0] + snc16[nc]), ex2(sH[1] + bbrH[1] + snc16[nc])),
                               pk2(ex2(sH[2] + bbrH[2] + snc16[nc]), ex2(sH[3] + bbrH[3] + snc16[nc])) };
                *reinterpret_cast<uintx2*>(&PtH[wv][nc * 16 + ln][rowb]) = pkd;
            } else {
                float p[4];
#pragma unroll
                for (int r = 0; r < 4; ++r) {
                    bool ok = (kln + nc * 16) <= (q0H + rowb + r);
                    float e = ex2(sH[r] + bbrH[r] + snc16[nc]);
                    p[r] = ok ? e : 0.0f;
                }
                uintx2 pkd = { pk2(p[0], p[1]), pk2(p[2], p[3]) };
                *reinterpret_cast<uintx2*>(&PtH[wv][nc * 16 + ln][rowb]) = pkd;
            }
            // light pack + store
            if (liveL) {
                if (!diagL) {
                    uintx2 pkd = { pk2(ex2(sL[0] + bbrL[0] + snc16[nc]), ex2(sL[1] + bbrL[1] + snc16[nc])),
                                   pk2(ex2(sL[2] + bbrL[2] + snc16[nc]), ex2(sL[3] + bbrL[3] + snc16[nc])) };
                    *reinterpret_cast<uintx2*>(&PtL[wv][nc * 16 + ln][rowb]) = pkd;
                } else {
                    float p[4];
#pragma unroll
                    for (int r = 0; r < 4; ++r) {
                        bool ok = (kln + nc * 16) <= (q0L + rowb + r);
                        float e = ex2(sL[r] + bbrL[r] + snc16[nc]);
                        p[r] = ok ? e : 0.0f;
                    }
                    uintx2 pkd = { pk2(p[0], p[1]), pk2(p[2], p[3]) };
                    *reinterpret_cast<uintx2*>(&PtL[wv][nc * 16 + ln][rowb]) = pkd;
                }
            }
        }

        __builtin_amdgcn_s_setprio(1);
#pragma unroll
        for (int kk = 0; kk < 2; ++kk) {
            const bool skipH = diagH && (kk * 32 > wv * 16 + 15);
            const bool goL = liveL && !(diagL && (kk * 32 > wv * 16 + 15));
            shortx8 pfH, pfL;
            if (!skipH) {
#pragma unroll
                for (int j = 0; j < 8; ++j) pfH[j] = PtH[wv][kk * 32 + qd + j][ln];
                lsumH = __builtin_amdgcn_mfma_f32_16x16x32_bf16(pfH, ones, lsumH, 0, 0, 0);
            }
            if (goL) {
#pragma unroll
                for (int j = 0; j < 8; ++j) pfL[j] = PtL[wv][kk * 32 + qd + j][ln];
                lsumL = __builtin_amdgcn_mfma_f32_16x16x32_bf16(pfL, ones, lsumL, 0, 0, 0);
            }
#pragma unroll
            for (int nc = 0; nc < 4; ++nc) {
                shortx8 bfr = *reinterpret_cast<const shortx8*>(&Vt[nc * 16 + ln][kk * 32 + qd]);
                if (!skipH) oaccH[nc] = __builtin_amdgcn_mfma_f32_16x16x32_bf16(pfH, bfr, oaccH[nc], 0, 0, 0);
                if (goL)   oaccL[nc] = __builtin_amdgcn_mfma_f32_16x16x32_bf16(pfL, bfr, oaccL[nc], 0, 0, 0);
            }
        }
        __builtin_amdgcn_s_setprio(0);
    }

#pragma unroll
    for (int r = 0; r < 4; ++r) {
        float invH = 1.0f / lsumH[r];
        float invL = 1.0f / lsumL[r];
        int tH = q0H + rowb + r;
        int tL = q0L + rowb + r;
#pragma unroll
        for (int nc = 0; nc < 4; ++nc) {
            ao[koff + (size_t)tH * HD_ + nc * 16 + ln] = f2bf(oaccH[nc][r] * invH);
            ao[koff + (size_t)tL * HD_ + nc * 16 + ln] = f2bf(oaccL[nc][r] * invL);
        }
    }
}

// ================= FALLBACK PATH (R8, fp32 inputs) =================
__global__ __launch_bounds__(256) void qkv_slow(const float* __restrict__ x,
                                                const float* __restrict__ wqkv,
                                                short* __restrict__ qout,
                                                short* __restrict__ kv) {
    __shared__ __align__(16) short As[64][72];
    __shared__ __align__(16) short Bs[64][72];
    const int tid = threadIdx.x;
    const int wv = tid >> 6, l = tid & 63, ln = l & 15, quad = l >> 4, qd = quad << 3;
    const int m0 = blockIdx.y * 64;
    const int sel = blockIdx.x >> 4, h = blockIdx.x & 15;
    const int nrow = sel * D_ + h * HD_;
    const int sr0 = tid >> 3, sc0 = (tid & 7) << 3, sr1 = sr0 + 32;
    floatx4 fa[4], fb[4];
    auto FETCH = [&](int k0) {
        const float* ap = &x[(size_t)(m0 + sr0) * D_ + k0 + sc0];
        fa[0] = *reinterpret_cast<const floatx4*>(ap);
        fa[1] = *reinterpret_cast<const floatx4*>(ap + 4);
        ap += (size_t)32 * D_;
        fa[2] = *reinterpret_cast<const floatx4*>(ap);
        fa[3] = *reinterpret_cast<const floatx4*>(ap + 4);
        const float* bp = &wqkv[(size_t)(nrow + sr0) * D_ + k0 + sc0];
        fb[0] = *reinterpret_cast<const floatx4*>(bp);
        fb[1] = *reinterpret_cast<const floatx4*>(bp + 4);
        bp += (size_t)32 * D_;
        fb[2] = *reinterpret_cast<const floatx4*>(bp);
        fb[3] = *reinterpret_cast<const floatx4*>(bp + 4);
    };
    floatx4 acc[4] = {};
    FETCH(0);
    for (int k0 = 0; k0 < D_; k0 += 64) {
        __syncthreads();
        *reinterpret_cast<shortx8*>(&As[sr0][sc0]) = cvt8(fa[0], fa[1]);
        *reinterpret_cast<shortx8*>(&As[sr1][sc0]) = cvt8(fa[2], fa[3]);
        *reinterpret_cast<shortx8*>(&Bs[sr0][sc0]) = cvt8(fb[0], fb[1]);
        *reinterpret_cast<shortx8*>(&Bs[sr1][sc0]) = cvt8(fb[2], fb[3]);
        __syncthreads();
        if (k0 + 64 < D_) FETCH(k0 + 64);
        const int mr = (wv << 4) + ln;
#pragma unroll
        for (int kk = 0; kk < 2; ++kk) {
            shortx8 a = *reinterpret_cast<const shortx8*>(&As[mr][kk * 32 + qd]);
#pragma unroll
            for (int nc = 0; nc < 4; ++nc) {
                shortx8 b = *reinterpret_cast<const shortx8*>(&Bs[nc * 16 + ln][kk * 32 + qd]);
                acc[nc] = __builtin_amdgcn_mfma_f32_16x16x32_bf16(a, b, acc[nc], 0, 0, 0);
            }
        }
    }
    const int bb = m0 >> 11, t0 = m0 & (T_ - 1);
    if (sel < 2) {
        short* dst = (sel == 0) ? qout : kv;
        const float sc = (sel == 0) ? QSCALE : 1.0f;   // Q carries log2e
#pragma unroll
        for (int r = 0; r < 4; ++r) {
            int t = t0 + (wv << 4) + (quad << 2) + r;
#pragma unroll
            for (int nc = 0; nc < 4; ++nc)
                dst[((size_t)(bb * H_ + h) * T_ + t) * HD_ + nc * 16 + ln] = f2bf(acc[nc][r] * sc);
        }
    } else {
        __syncthreads();
#pragma unroll
        for (int r = 0; r < 4; ++r)
#pragma unroll
            for (int nc = 0; nc < 4; ++nc)
                As[nc * 16 + ln][(wv << 4) + (quad << 2) + r] = f2bf(acc[nc][r]);
        __syncthreads();
        const int d = tid >> 2, tseg = (tid & 3) << 4;
        short* vdst = kv + FULLH + ((size_t)(bb * H_ + h) * HD_ + d) * T_ + t0 + tseg;
        *reinterpret_cast<shortx8*>(vdst)     = *reinterpret_cast<const shortx8*>(&As[d][tseg]);
        *reinterpret_cast<shortx8*>(vdst + 8) = *reinterpret_cast<const shortx8*>(&As[d][tseg + 8]);
    }
}

__global__ __launch_bounds__(256) void out_slow(const short* __restrict__ A,
                                                const float* __restrict__ W,
                                                float* __restrict__ out) {
    __shared__ __align__(16) short As[64][72];
    __shared__ __align__(16) short Bs[64][72];
    const int tid = threadIdx.x;
    const int wv = tid >> 6, l = tid & 63, ln = l & 15, quad = l >> 4, qd = quad << 3;
    const int m0 = blockIdx.y * 64, n0 = blockIdx.x * 64;
    const int sr0 = tid >> 3, sc0 = (tid & 7) << 3, sr1 = sr0 + 32;
    shortx8 sa0, sa1;
    floatx4 fb[4];
    auto FETCH = [&](int k0) {
        const int h = k0 >> 6;
        int m = m0 + sr0;
        int bb = m >> 11, t = m & (T_ - 1);
        sa0 = *reinterpret_cast<const shortx8*>(A + ((size_t)(bb * H_ + h) * T_ + t) * HD_ + sc0);
        m = m0 + sr1; bb = m >> 11; t = m & (T_ - 1);
        sa1 = *reinterpret_cast<const shortx8*>(A + ((size_t)(bb * H_ + h) * T_ + t) * HD_ + sc0);
        const float* bp = &W[(size_t)(n0 + sr0) * D_ + k0 + sc0];
        fb[0] = *reinterpret_cast<const floatx4*>(bp);
        fb[1] = *reinterpret_cast<const floatx4*>(bp + 4);
        bp += (size_t)32 * D_;
        fb[2] = *reinterpret_cast<const floatx4*>(bp);
        fb[3] = *reinterpret_cast<const floatx4*>(bp + 4);
    };
    floatx4 acc[4] = {};
    FETCH(0);
    for (int k0 = 0; k0 < D_; k0 += 64) {
        __syncthreads();
        *reinterpret_cast<shortx8*>(&As[sr0][sc0]) = sa0;
        *reinterpret_cast<shortx8*>(&As[sr1][sc0]) = sa1;
        *reinterpret_cast<shortx8*>(&Bs[sr0][sc0]) = cvt8(fb[0], fb[1]);
        *reinterpret_cast<shortx8*>(&Bs[sr1][sc0]) = cvt8(fb[2], fb[3]);
        __syncthreads();
        if (k0 + 64 < D_) FETCH(k0 + 64);
        const int mr = (wv << 4) + ln;
#pragma unroll
        for (int kk = 0; kk < 2; ++kk) {
            shortx8 a = *reinterpret_cast<const shortx8*>(&As[mr][kk * 32 + qd]);
#pragma unroll
            for (int nc = 0; nc < 4; ++nc) {
                shortx8 b = *reinterpret_cast<const shortx8*>(&Bs[nc * 16 + ln][kk * 32 + qd]);
                acc[nc] = __builtin_amdgcn_mfma_f32_16x16x32_bf16(a, b, acc[nc], 0, 0, 0);
            }
        }
    }
#pragma unroll
    for (int r = 0; r < 4; ++r) {
        int m = m0 + (wv << 4) + (quad << 2) + r;
#pragma unroll
        for (int nc = 0; nc < 4; ++nc)
            out[(size_t)m * D_ + n0 + nc * 16 + ln] = acc[nc][r];
    }
}

extern "C" void kernel_launch(void* const* d_in, const int* in_sizes, int n_in,
                              void* d_out, int out_size, void* d_ws, size_t ws_size,
                              hipStream_t stream) {
    const float* x    = (const float*)d_in[0];
    const float* wqkv = (const float*)d_in[1];
    const float* wout = (const float*)d_in[2];

    short* kvbuf = (short*)d_out;    // K head-major + V dim-major bf16: 16MB
    float* out   = (float*)d_out;

    if (ws_size >= 23068672ULL) {    // 22 MiB fast path
        short* xbf  = (short*)d_ws;            // 4M shorts
        short* wbf  = xbf + 4 * 1024 * 1024;   // 3M shorts
        short* qws  = xbf + 7 * 1024 * 1024;   // 4M shorts (Q, then attn out in place)
        short* wobf = xbf;                     // overlays dead xbf after qkv_fast

        cvt_xw<<<3584, 256, 0, stream>>>(x, wqkv, xbf, wbf);
        qkv_fast<<<dim3(24, 32), 256, 0, stream>>>(xbf, wbf, qws, kvbuf);
        attn<<<dim3(1024), 256, 0, stream>>>(qws, kvbuf, qws, wout, wobf);
        out_fast<<<dim3(8, 32), 256, 0, stream>>>(qws, wobf, out);
    } else {                          // proven R8 fallback
        short* qws = (short*)d_ws;
        qkv_slow<<<dim3(48, 64), 256, 0, stream>>>(x, wqkv, qws, kvbuf);
        attn<<<dim3(512), 256, 0, stream>>>(qws, kvbuf, qws, nullptr, nullptr);
        out_slow<<<dim3(16, 64), 256, 0, stream>>>(qws, wout, out);
    }
}

// Round 3
// 182.016 us; speedup vs baseline: 1.1453x; 1.1453x over previous
//
#include <hip/hip_runtime.h>
#include <hip/hip_bf16.h>

typedef __attribute__((ext_vector_type(8))) short shortx8;
typedef __attribute__((ext_vector_type(4))) float floatx4;
typedef __attribute__((ext_vector_type(16))) float floatx16;
typedef __attribute__((ext_vector_type(4))) unsigned uintx4;
typedef __attribute__((ext_vector_type(2))) unsigned uintx2;

#define B_ 2
#define T_ 2048
#define D_ 1024
#define H_ 16
#define HD_ 64
#define SCALE 0.125f
// log2(e)-folded constants: Q is pre-scaled by SCALE*log2e, softmax uses exp2.
#define QSCALE 0.18033688011112042f   /* 0.125 * log2(e) */
#define SMAX2 23.083120654223414f     /* 16 * log2(e) */
#define FULLH ((size_t)B_ * H_ * T_ * HD_)

// async global->LDS, 16B per lane; LDS dest = wave-uniform base + lane*16
#define GLDS16(g, l) __builtin_amdgcn_global_load_lds( \
    (__attribute__((address_space(1))) void*)(g), \
    (__attribute__((address_space(3))) void*)(l), 16, 0, 0)

__device__ __forceinline__ short f2bf(float f) {
    union { float f; unsigned u; } v; v.f = f;
    unsigned r = v.u + 0x7FFFu + ((v.u >> 16) & 1u);
    return (short)(r >> 16);
}

__device__ __forceinline__ unsigned pk2(float x, float y) {
    union { __hip_bfloat162 h; unsigned u; } t;
    t.h = __float22bfloat162_rn(make_float2(x, y));
    return t.u;
}

__device__ __forceinline__ shortx8 cvt8(floatx4 a, floatx4 b) {
    uintx4 r = { pk2(a[0], a[1]), pk2(a[2], a[3]), pk2(b[0], b[1]), pk2(b[2], b[3]) };
    return __builtin_bit_cast(shortx8, r);
}

__device__ __forceinline__ float ex2(float x) {
#if __has_builtin(__builtin_amdgcn_exp2f)
    return __builtin_amdgcn_exp2f(x);
#else
    return exp2f(x);
#endif
}

// ---------------- fp32 -> bf16 bulk convert (x + w_qkv merged, one launch) ----
__global__ __launch_bounds__(256) void cvt_xw(const float* __restrict__ x,
                                              const float* __restrict__ wqkv,
                                              short* __restrict__ xbf,
                                              short* __restrict__ wbf) {
    int i = blockIdx.x * 256 + threadIdx.x;
    const float* src; short* dst; int o;
    if (i < 524288) { src = x; dst = xbf; o = i; }
    else            { src = wqkv; dst = wbf; o = i - 524288; }
    const floatx4* p = reinterpret_cast<const floatx4*>(src) + (size_t)o * 2;
    *(reinterpret_cast<shortx8*>(dst) + o) = cvt8(p[0], p[1]);
}

// ================= FAST PATH (bf16 inputs, m97-style) =================
// Q/K/V projection. grid (24,32): n0g = bx*128 (sel = n0g>>10), m-tile by.
__global__ __launch_bounds__(256) void qkv_fast(const short* __restrict__ xbf,
                                                const short* __restrict__ wbf,
                                                short* __restrict__ qout,
                                                short* __restrict__ kv) {
    __shared__ __align__(16) short As[128 * 64];
    __shared__ __align__(16) short Bs[128 * 64];

    const int tid = threadIdx.x;
    const int wv = tid >> 6;
    const int l  = tid & 63;
    const int ln = l & 15;
    const int quad = l >> 4;
    const int rowb = quad << 2;
    const int wm = wv >> 1, wn = wv & 1;
    const int m0 = blockIdx.y * 128;
    const int n0g = blockIdx.x * 128;

    const int lr = l >> 3, lc = l & 7;
    const int gcol = (lc ^ lr) << 3;                 // swizzled source chunk
    const short* agp = xbf + (size_t)(m0 + wv * 32 + lr) * D_ + gcol;
    const short* bgp = wbf + (size_t)(n0g + wv * 32 + lr) * D_ + gcol;
    short* aldsb = As + wv * 32 * 64;
    short* bldsb = Bs + wv * 32 * 64;

    floatx4 acc[4][4] = {};

    for (int k0 = 0; k0 < D_; k0 += 64) {
        __syncthreads();
#pragma unroll
        for (int c = 0; c < 4; ++c) {
            GLDS16(agp + (size_t)(c * 8) * D_ + k0, aldsb + c * 512);
            GLDS16(bgp + (size_t)(c * 8) * D_ + k0, bldsb + c * 512);
        }
        __syncthreads();

#pragma unroll
        for (int kk = 0; kk < 2; ++kk) {
            const int csw = (kk << 2) + quad;
            const int sw = (csw ^ (ln & 7)) << 3;
            shortx8 af[4], bf[4];
#pragma unroll
            for (int i = 0; i < 4; ++i)
                af[i] = *reinterpret_cast<const shortx8*>(&As[((wm * 64 + i * 16 + ln) << 6) + sw]);
#pragma unroll
            for (int j = 0; j < 4; ++j)
                bf[j] = *reinterpret_cast<const shortx8*>(&Bs[((wn * 64 + j * 16 + ln) << 6) + sw]);
#pragma unroll
            for (int i = 0; i < 4; ++i)
#pragma unroll
                for (int j = 0; j < 4; ++j)
                    acc[i][j] = __builtin_amdgcn_mfma_f32_16x16x32_bf16(af[i], bf[j], acc[i][j], 0, 0, 0);
        }
    }

    const int sel = n0g >> 10;
    const int bb = m0 >> 11;
    const int t0w = (m0 + wm * 64) & (T_ - 1);
    const int h = ((n0g + wn * 64) >> 6) & 15;

    if (sel < 2) {
        short* dst = (sel == 0) ? qout : kv;
        const float sc = (sel == 0) ? QSCALE : 1.0f;   // Q carries log2e
        const size_t hb = (size_t)(bb * H_ + h) * T_;
#pragma unroll
        for (int i = 0; i < 4; ++i)
#pragma unroll
            for (int r = 0; r < 4; ++r) {
                int t = t0w + i * 16 + rowb + r;
#pragma unroll
                for (int j = 0; j < 4; ++j)
                    dst[(hb + t) * HD_ + j * 16 + ln] = f2bf(acc[i][j][r] * sc);
            }
    } else {
        // V -> dim-major [b][h][d][t], 2-pass per-wave LDS transpose (As/Bs dead)
        __syncthreads();
        short* tb = (wv < 2) ? (As + wv * 4096) : (Bs + (wv - 2) * 4096);  // 32x72 region
        short* vhead = kv + FULLH + (size_t)(bb * H_ + h) * HD_ * T_;
        const int dl = l & 31, th = (l >> 5) << 5;
#pragma unroll
        for (int p = 0; p < 2; ++p) {
#pragma unroll
            for (int i = 0; i < 4; ++i)
#pragma unroll
                for (int jj = 0; jj < 2; ++jj) {
                    int j = 2 * p + jj;
#pragma unroll
                    for (int r = 0; r < 4; ++r)
                        tb[(jj * 16 + ln) * 72 + i * 16 + rowb + r] = f2bf(acc[i][j][r]);
                }
            short* vd = vhead + (size_t)(p * 32 + dl) * T_ + t0w + th;
#pragma unroll
            for (int seg = 0; seg < 4; ++seg)
                *reinterpret_cast<shortx8*>(vd + seg * 8) =
                    *reinterpret_cast<const shortx8*>(&tb[dl * 72 + th + seg * 8]);
        }
    }
}

// Final projection. grid (8,32). A = attn out, bf16 head-major. W bf16 row-major.
__global__ __launch_bounds__(256) void out_fast(const short* __restrict__ Abf,
                                                const short* __restrict__ wbf,
                                                float* __restrict__ out) {
    __shared__ __align__(16) short As[128 * 64];
    __shared__ __align__(16) short Bs[128 * 64];

    const int tid = threadIdx.x;
    const int wv = tid >> 6;
    const int l  = tid & 63;
    const int ln = l & 15;
    const int quad = l >> 4;
    const int rowb = quad << 2;
    const int wm = wv >> 1, wn = wv & 1;
    const int m0 = blockIdx.y * 128;
    const int n0g = blockIdx.x * 128;

    const int lr = l >> 3, lc = l & 7;
    const int gcol = (lc ^ lr) << 3;
    const short* bgp = wbf + (size_t)(n0g + wv * 32 + lr) * D_ + gcol;
    short* aldsb = As + wv * 32 * 64;
    short* bldsb = Bs + wv * 32 * 64;

    size_t abase[4];
#pragma unroll
    for (int c = 0; c < 4; ++c) {
        int m = m0 + wv * 32 + c * 8 + lr;
        int bb2 = m >> 11, t = m & (T_ - 1);
        abase[c] = ((size_t)(bb2 * H_) * T_ + t) * HD_ + gcol;
    }

    floatx4 acc[4][4] = {};

    for (int k0 = 0; k0 < D_; k0 += 64) {
        const size_t hoff = (size_t)(k0 >> 6) * T_ * HD_;
        __syncthreads();
#pragma unroll
        for (int c = 0; c < 4; ++c) {
            GLDS16(Abf + abase[c] + hoff, aldsb + c * 512);
            GLDS16(bgp + (size_t)(c * 8) * D_ + k0, bldsb + c * 512);
        }
        __syncthreads();

#pragma unroll
        for (int kk = 0; kk < 2; ++kk) {
            const int csw = (kk << 2) + quad;
            const int sw = (csw ^ (ln & 7)) << 3;
            shortx8 af[4], bf[4];
#pragma unroll
            for (int i = 0; i < 4; ++i)
                af[i] = *reinterpret_cast<const shortx8*>(&As[((wm * 64 + i * 16 + ln) << 6) + sw]);
#pragma unroll
            for (int j = 0; j < 4; ++j)
                bf[j] = *reinterpret_cast<const shortx8*>(&Bs[((wn * 64 + j * 16 + ln) << 6) + sw]);
#pragma unroll
            for (int i = 0; i < 4; ++i)
#pragma unroll
                for (int j = 0; j < 4; ++j)
                    acc[i][j] = __builtin_amdgcn_mfma_f32_16x16x32_bf16(af[i], bf[j], acc[i][j], 0, 0, 0);
        }
    }

#pragma unroll
    for (int i = 0; i < 4; ++i)
#pragma unroll
        for (int r = 0; r < 4; ++r) {
            int m = m0 + wm * 64 + i * 16 + rowb + r;
#pragma unroll
            for (int j = 0; j < 4; ++j)
                out[(size_t)m * D_ + n0g + wn * 64 + j * 16 + ln] = acc[i][j][r];
        }
}

// ---------------- flash attention, 32x32 MFMA, in-register softmax ----------
// Block = 128 threads (2 waves), each wave owns 32 q-rows (QBLK=64/block).
// S^T = mfma(K,Q) so each lane holds P for q = lane&31 -> softmax lane-local;
// P -> PV A-operand via pk2 + v_permlane32_swap (no P LDS round-trip).
// lsum rides mfma(P, ones) -> same reg layout as O -> lane-local normalize.
// Grid 0..1023 attn (balanced qblk map, 4 heads/XCD); >=1024 convert w_out.
__global__ __launch_bounds__(128, 2) void attn(const short* __restrict__ qws,
                                               const short* __restrict__ kv,
                                               short* ao,
                                               const float* __restrict__ wout,
                                               short* __restrict__ wobf) {
    if (blockIdx.x >= 1024) {
        int i = (blockIdx.x - 1024) * 128 + threadIdx.x;   // 1024 blocks -> 131072 groups
        const floatx4* p = reinterpret_cast<const floatx4*>(wout) + (size_t)i * 2;
        *(reinterpret_cast<shortx8*>(wobf) + i) = cvt8(p[0], p[1]);
        return;
    }

    __shared__ __align__(16) short Ks[64][72];
    __shared__ __align__(16) short Vt[64][72];

    const int tid = threadIdx.x;
    const int wv = tid >> 6;          // 0,1
    const int l  = tid & 63;
    const int ql = l & 31;
    const int hi = l >> 5;

    // balanced mapping: rounds t=0..3 per CU get qblk {31-r, r, 23-r, 8+r}
    const int id  = blockIdx.x;
    const int xcd = id & 7;
    const int u2  = (id >> 3) & 3;
    const int rr  = (id >> 5) & 7;
    const int tt  = id >> 8;
    const int bh  = xcd * 4 + u2;     // 4 heads per XCD
    const int qblk = (tt == 0) ? 31 - rr : (tt == 1) ? rr : (tt == 2) ? 23 - rr : 8 + rr;
    const int h = bh & 15, b = bh >> 4;

    const float slope2 = 1.4426950408889634f * exp2f(-(float)(h + 1) * 0.0625f);
    const size_t koff = (size_t)(b * H_ + h) * T_ * HD_;
    const int q0w = qblk * 64 + wv * 32;

    // Q fragments (B-operand): qf[ds] = Q[q0w+ql][ds*16 + hi*8 + 0..7]
    shortx8 qf[4];
#pragma unroll
    for (int ds = 0; ds < 4; ++ds)
        qf[ds] = *reinterpret_cast<const shortx8*>(&qws[koff + (size_t)(q0w + ql) * HD_ + ds * 16 + hi * 8]);

    // per-lane softmax bias base: exponent = s + rb[g] + slope2*(kb*64 + nc*32)
    const float cbase = slope2 * (float)(4 * hi - (q0w + ql)) - SMAX2;
    float rb[16];
#pragma unroll
    for (int g = 0; g < 16; ++g)
        rb[g] = cbase + slope2 * (float)((g & 3) + 8 * (g >> 2));
    const float s32 = slope2 * 32.0f;

    // staging: thread -> 64B contiguous of K row sr and V row sr
    const int sr = tid >> 1;
    const int sc = (tid & 1) << 5;
    const short* kbase = kv + koff;
    const short* vbase = kv + FULLH + koff;
    shortx8 kR[4], vR[4];
    auto FETCH = [&](int kb) {
        const short* kp = kbase + (((size_t)(kb * 64 + sr)) << 6) + sc;
        const short* vp = vbase + (size_t)sr * T_ + kb * 64 + sc;
#pragma unroll
        for (int s = 0; s < 4; ++s) {
            kR[s] = *reinterpret_cast<const shortx8*>(kp + 8 * s);
            vR[s] = *reinterpret_cast<const shortx8*>(vp + 8 * s);
        }
    };

    floatx16 oacc0 = {}, oacc1 = {}, lsum = {};
    const shortx8 ones = {16256, 16256, 16256, 16256, 16256, 16256, 16256, 16256};
    const int qlh = ql - 4 * hi;

    FETCH(0);
    for (int kb = 0; kb <= qblk; ++kb) {
        __syncthreads();
#pragma unroll
        for (int s = 0; s < 4; ++s) {
            *reinterpret_cast<shortx8*>(&Ks[sr][sc + 8 * s]) = kR[s];
            *reinterpret_cast<shortx8*>(&Vt[sr][sc + 8 * s]) = vR[s];
        }
        __syncthreads();
        if (kb < qblk) FETCH(kb + 1);

        const bool diag = (kb == qblk);
        const float tb = slope2 * (float)(kb * 64);

#pragma unroll
        for (int nc = 0; nc < 2; ++nc) {
            const bool act = !diag || (nc == 0) || (wv == 1);
            if (!act) continue;                     // wave-uniform
            const bool part = diag && (nc == wv);   // partial causal mask

            floatx16 s = {};
#pragma unroll
            for (int ds = 0; ds < 4; ++ds) {
                shortx8 kf = *reinterpret_cast<const shortx8*>(&Ks[nc * 32 + ql][ds * 16 + hi * 8]);
                s = __builtin_amdgcn_mfma_f32_32x32x16_bf16(kf, qf[ds], s, 0, 0, 0);
            }

            const float tnc = tb + (nc ? s32 : 0.0f);
            float p[16];
#pragma unroll
            for (int g = 0; g < 16; ++g) {
                float e = ex2(s[g] + rb[g] + tnc);
                if (part) {
                    const int kc = (g & 3) + 8 * (g >> 2);
                    e = (kc <= qlh) ? e : 0.0f;
                }
                p[g] = e;
            }

            unsigned cv[4][2];
#pragma unroll
            for (int g = 0; g < 4; ++g) {
                cv[g][0] = pk2(p[4 * g + 0], p[4 * g + 1]);
                cv[g][1] = pk2(p[4 * g + 2], p[4 * g + 3]);
            }

            __builtin_amdgcn_s_setprio(1);
#pragma unroll
            for (int kh = 0; kh < 2; ++kh) {
                unsigned w0 = cv[2 * kh][0], w2 = cv[2 * kh + 1][0];
                unsigned w1 = cv[2 * kh][1], w3 = cv[2 * kh + 1][1];
                asm volatile("v_permlane32_swap_b32 %0, %1" : "+v"(w0), "+v"(w2));
                asm volatile("v_permlane32_swap_b32 %0, %1" : "+v"(w1), "+v"(w3));
                uintx4 uu = {w0, w1, w2, w3};
                shortx8 apv = __builtin_bit_cast(shortx8, uu);
                const int ks = nc * 2 + kh;
                lsum = __builtin_amdgcn_mfma_f32_32x32x16_bf16(apv, ones, lsum, 0, 0, 0);
                shortx8 vf0 = *reinterpret_cast<const shortx8*>(&Vt[ql][ks * 16 + hi * 8]);
                oacc0 = __builtin_amdgcn_mfma_f32_32x32x16_bf16(apv, vf0, oacc0, 0, 0, 0);
                shortx8 vf1 = *reinterpret_cast<const shortx8*>(&Vt[32 + ql][ks * 16 + hi * 8]);
                oacc1 = __builtin_amdgcn_mfma_f32_32x32x16_bf16(apv, vf1, oacc1, 0, 0, 0);
            }
            __builtin_amdgcn_s_setprio(0);
        }
    }

    // epilogue: O and lsum share layout -> lane-local normalize
#pragma unroll
    for (int g = 0; g < 16; ++g) {
        const int qrow = (g & 3) + 8 * (g >> 2) + 4 * hi;
        const float inv = 1.0f / lsum[g];
        const size_t ob = koff + (size_t)(q0w + qrow) * HD_ + ql;
        ao[ob]      = f2bf(oacc0[g] * inv);
        ao[ob + 32] = f2bf(oacc1[g] * inv);
    }
}

// ================= FALLBACK PATH (R8, fp32 inputs) =================
__global__ __launch_bounds__(256) void qkv_slow(const float* __restrict__ x,
                                                const float* __restrict__ wqkv,
                                                short* __restrict__ qout,
                                                short* __restrict__ kv) {
    __shared__ __align__(16) short As[64][72];
    __shared__ __align__(16) short Bs[64][72];
    const int tid = threadIdx.x;
    const int wv = tid >> 6, l = tid & 63, ln = l & 15, quad = l >> 4, qd = quad << 3;
    const int m0 = blockIdx.y * 64;
    const int sel = blockIdx.x >> 4, h = blockIdx.x & 15;
    const int nrow = sel * D_ + h * HD_;
    const int sr0 = tid >> 3, sc0 = (tid & 7) << 3, sr1 = sr0 + 32;
    floatx4 fa[4], fb[4];
    auto FETCH = [&](int k0) {
        const float* ap = &x[(size_t)(m0 + sr0) * D_ + k0 + sc0];
        fa[0] = *reinterpret_cast<const floatx4*>(ap);
        fa[1] = *reinterpret_cast<const floatx4*>(ap + 4);
        ap += (size_t)32 * D_;
        fa[2] = *reinterpret_cast<const floatx4*>(ap);
        fa[3] = *reinterpret_cast<const floatx4*>(ap + 4);
        const float* bp = &wqkv[(size_t)(nrow + sr0) * D_ + k0 + sc0];
        fb[0] = *reinterpret_cast<const floatx4*>(bp);
        fb[1] = *reinterpret_cast<const floatx4*>(bp + 4);
        bp += (size_t)32 * D_;
        fb[2] = *reinterpret_cast<const floatx4*>(bp);
        fb[3] = *reinterpret_cast<const floatx4*>(bp + 4);
    };
    floatx4 acc[4] = {};
    FETCH(0);
    for (int k0 = 0; k0 < D_; k0 += 64) {
        __syncthreads();
        *reinterpret_cast<shortx8*>(&As[sr0][sc0]) = cvt8(fa[0], fa[1]);
        *reinterpret_cast<shortx8*>(&As[sr1][sc0]) = cvt8(fa[2], fa[3]);
        *reinterpret_cast<shortx8*>(&Bs[sr0][sc0]) = cvt8(fb[0], fb[1]);
        *reinterpret_cast<shortx8*>(&Bs[sr1][sc0]) = cvt8(fb[2], fb[3]);
        __syncthreads();
        if (k0 + 64 < D_) FETCH(k0 + 64);
        const int mr = (wv << 4) + ln;
#pragma unroll
        for (int kk = 0; kk < 2; ++kk) {
            shortx8 a = *reinterpret_cast<const shortx8*>(&As[mr][kk * 32 + qd]);
#pragma unroll
            for (int nc = 0; nc < 4; ++nc) {
                shortx8 bq = *reinterpret_cast<const shortx8*>(&Bs[nc * 16 + ln][kk * 32 + qd]);
                acc[nc] = __builtin_amdgcn_mfma_f32_16x16x32_bf16(a, bq, acc[nc], 0, 0, 0);
            }
        }
    }
    const int bb = m0 >> 11, t0 = m0 & (T_ - 1);
    if (sel < 2) {
        short* dst = (sel == 0) ? qout : kv;
        const float sc = (sel == 0) ? QSCALE : 1.0f;   // Q carries log2e
#pragma unroll
        for (int r = 0; r < 4; ++r) {
            int t = t0 + (wv << 4) + (quad << 2) + r;
#pragma unroll
            for (int nc = 0; nc < 4; ++nc)
                dst[((size_t)(bb * H_ + h) * T_ + t) * HD_ + nc * 16 + ln] = f2bf(acc[nc][r] * sc);
        }
    } else {
        __syncthreads();
#pragma unroll
        for (int r = 0; r < 4; ++r)
#pragma unroll
            for (int nc = 0; nc < 4; ++nc)
                As[nc * 16 + ln][(wv << 4) + (quad << 2) + r] = f2bf(acc[nc][r]);
        __syncthreads();
        const int d = tid >> 2, tseg = (tid & 3) << 4;
        short* vdst = kv + FULLH + ((size_t)(bb * H_ + h) * HD_ + d) * T_ + t0 + tseg;
        *reinterpret_cast<shortx8*>(vdst)     = *reinterpret_cast<const shortx8*>(&As[d][tseg]);
        *reinterpret_cast<shortx8*>(vdst + 8) = *reinterpret_cast<const shortx8*>(&As[d][tseg + 8]);
    }
}

__global__ __launch_bounds__(256) void out_slow(const short* __restrict__ A,
                                                const float* __restrict__ W,
                                                float* __restrict__ out) {
    __shared__ __align__(16) short As[64][72];
    __shared__ __align__(16) short Bs[64][72];
    const int tid = threadIdx.x;
    const int wv = tid >> 6, l = tid & 63, ln = l & 15, quad = l >> 4, qd = quad << 3;
    const int m0 = blockIdx.y * 64, n0 = blockIdx.x * 64;
    const int sr0 = tid >> 3, sc0 = (tid & 7) << 3, sr1 = sr0 + 32;
    shortx8 sa0, sa1;
    floatx4 fb[4];
    auto FETCH = [&](int k0) {
        const int h = k0 >> 6;
        int m = m0 + sr0;
        int bb = m >> 11, t = m & (T_ - 1);
        sa0 = *reinterpret_cast<const shortx8*>(A + ((size_t)(bb * H_ + h) * T_ + t) * HD_ + sc0);
        m = m0 + sr1; bb = m >> 11; t = m & (T_ - 1);
        sa1 = *reinterpret_cast<const shortx8*>(A + ((size_t)(bb * H_ + h) * T_ + t) * HD_ + sc0);
        const float* bp = &W[(size_t)(n0 + sr0) * D_ + k0 + sc0];
        fb[0] = *reinterpret_cast<const floatx4*>(bp);
        fb[1] = *reinterpret_cast<const floatx4*>(bp + 4);
        bp += (size_t)32 * D_;
        fb[2] = *reinterpret_cast<const floatx4*>(bp);
        fb[3] = *reinterpret_cast<const floatx4*>(bp + 4);
    };
    floatx4 acc[4] = {};
    FETCH(0);
    for (int k0 = 0; k0 < D_; k0 += 64) {
        __syncthreads();
        *reinterpret_cast<shortx8*>(&As[sr0][sc0]) = sa0;
        *reinterpret_cast<shortx8*>(&As[sr1][sc0]) = sa1;
        *reinterpret_cast<shortx8*>(&Bs[sr0][sc0]) = cvt8(fb[0], fb[1]);
        *reinterpret_cast<shortx8*>(&Bs[sr1][sc0]) = cvt8(fb[2], fb[3]);
        __syncthreads();
        if (k0 + 64 < D_) FETCH(k0 + 64);
        const int mr = (wv << 4) + ln;
#pragma unroll
        for (int kk = 0; kk < 2; ++kk) {
            shortx8 a = *reinterpret_cast<const shortx8*>(&As[mr][kk * 32 + qd]);
#pragma unroll
            for (int nc = 0; nc < 4; ++nc) {
                shortx8 bq = *reinterpret_cast<const shortx8*>(&Bs[nc * 16 + ln][kk * 32 + qd]);
                acc[nc] = __builtin_amdgcn_mfma_f32_16x16x32_bf16(a, bq, acc[nc], 0, 0, 0);
            }
        }
    }
#pragma unroll
    for (int r = 0; r < 4; ++r) {
        int m = m0 + (wv << 4) + (quad << 2) + r;
#pragma unroll
        for (int nc = 0; nc < 4; ++nc)
            out[(size_t)m * D_ + n0 + nc * 16 + ln] = acc[nc][r];
    }
}

extern "C" void kernel_launch(void* const* d_in, const int* in_sizes, int n_in,
                              void* d_out, int out_size, void* d_ws, size_t ws_size,
                              hipStream_t stream) {
    const float* x    = (const float*)d_in[0];
    const float* wqkv = (const float*)d_in[1];
    const float* wout = (const float*)d_in[2];

    short* kvbuf = (short*)d_out;    // K head-major + V dim-major bf16: 16MB
    float* out   = (float*)d_out;

    if (ws_size >= 23068672ULL) {    // 22 MiB fast path
        short* xbf  = (short*)d_ws;            // 4M shorts
        short* wbf  = xbf + 4 * 1024 * 1024;   // 3M shorts
        short* qws  = xbf + 7 * 1024 * 1024;   // 4M shorts (Q, then attn out in place)
        short* wobf = xbf;                     // overlays dead xbf after qkv_fast

        cvt_xw<<<3584, 256, 0, stream>>>(x, wqkv, xbf, wbf);
        qkv_fast<<<dim3(24, 32), 256, 0, stream>>>(xbf, wbf, qws, kvbuf);
        attn<<<dim3(2048), 128, 0, stream>>>(qws, kvbuf, qws, wout, wobf);
        out_fast<<<dim3(8, 32), 256, 0, stream>>>(qws, wobf, out);
    } else {                          // proven R8 fallback
        short* qws = (short*)d_ws;
        qkv_slow<<<dim3(48, 64), 256, 0, stream>>>(x, wqkv, qws, kvbuf);
        attn<<<dim3(1024), 128, 0, stream>>>(qws, kvbuf, qws, nullptr, nullptr);
        out_slow<<<dim3(16, 64), 256, 0, stream>>>(qws, wout, out);
    }
}